// Round 1
// baseline (561.490 us; speedup 1.0000x reference)
//
#include <hip/hip_runtime.h>
#include <hip/hip_bf16.h>

// AttnBlock2d: GN -> q/k/v 1x1conv -> softmax(q^T k / sqrt(C)) -> v@alpha -> proj -> +x
// B=8, C=256, N=H*W=4096. bf16 MFMA pipeline, fp32 accumulation.
// ws layout: [0,16M) h_t/attn_out [B][N][C] bf16 ; [16M,32M) q_t ; [32M,48M) k_t ;
//            [48M,64M) v_c [B][C][N] ; [64M,+512K) bf16 weights wq|wk|wv|wp

typedef unsigned int u32;
typedef unsigned short u16;
typedef __bf16 bf16x8 __attribute__((ext_vector_type(8)));
typedef float f32x4 __attribute__((ext_vector_type(4)));

#define GAS __attribute__((address_space(1)))
#define LAS __attribute__((address_space(3)))

__device__ __forceinline__ u16 f2bf(float f) {
  union { float f; u32 u; } v; v.f = f;
  return (u16)((v.u + 0x7fffu + ((v.u >> 16) & 1u)) >> 16);
}

__device__ __forceinline__ f32x4 mfma16(bf16x8 a, bf16x8 b, f32x4 c) {
  return __builtin_amdgcn_mfma_f32_16x16x32_bf16(a, b, c, 0, 0, 0);
}

// Stage a [ROWS][ROWB bytes] row-major bf16 tile into linear LDS via global_load_lds,
// with XOR swizzle applied on the SOURCE side (rule #21: linear dest + inverse-swz source).
// Semantic colbyte of linear slot s in row r is s ^ ((r&7)<<4).
template<int ROWB, int ITERS>
__device__ __forceinline__ void stage_swz(u16* lds, const u16* g, int ldg, int tid) {
#pragma unroll
  for (int it = 0; it < ITERS; ++it) {
    int idx = it * 256 + tid;
    int off = idx * 16;                 // linear LDS byte offset
    int row = off / ROWB;
    int slot = off % ROWB;
    int sem = slot ^ ((row & 7) << 4);  // semantic byte-in-row
    const u16* src = g + (long)row * ldg + (sem >> 1);
    u16* dst = lds + (long)(idx & ~63) * 8;   // wave-uniform base; HW adds lane*16B
    __builtin_amdgcn_global_load_lds((const GAS u32*)src, (LAS u32*)dst, 16, 0, 0);
  }
}

// Read a 16B MFMA fragment from a swizzled tile: semantic (row, kbyte) -> swizzled addr.
template<int ROWB>
__device__ __forceinline__ bf16x8 ldfrag(const u16* lds, int row, int kbyte) {
  int off = row * ROWB + (kbyte ^ ((row & 7) << 4));
  return *(const bf16x8*)((const char*)lds + off);
}

// ---------------- weight fp32 -> bf16 ----------------
__global__ __launch_bounds__(256) void convert_w(
    const float* __restrict__ w0, const float* __restrict__ w1,
    const float* __restrict__ w2, const float* __restrict__ w3,
    u16* __restrict__ out) {
  int i = blockIdx.x * 256 + threadIdx.x;      // 0 .. 262143
  int seg = i >> 16, idx = i & 65535;
  const float* w = seg == 0 ? w0 : seg == 1 ? w1 : seg == 2 ? w2 : w3;
  out[i] = f2bf(w[idx]);
}

// ---------------- GroupNorm: x [B][C][N] fp32 -> h_t [B][N][C] bf16 ----------------
__global__ __launch_bounds__(256) void gn_kernel(
    const float* __restrict__ x, const float* __restrict__ gamma,
    const float* __restrict__ beta, u16* __restrict__ ht) {
  int tid = threadIdx.x;
  int b = blockIdx.x >> 4;
  int grp = blockIdx.x & 15;
  const float* xg = x + ((long)b * 256 + grp * 16) * 4096;

  float s = 0.f, ss = 0.f;
  const float4* x4 = (const float4*)xg;        // 16*4096 = 65536 floats = 16384 float4
#pragma unroll 4
  for (int it = 0; it < 64; ++it) {
    float4 v = x4[it * 256 + tid];
    s += v.x + v.y + v.z + v.w;
    ss += v.x * v.x + v.y * v.y + v.z * v.z + v.w * v.w;
  }
#pragma unroll
  for (int d = 1; d < 64; d <<= 1) {
    s += __shfl_xor(s, d);
    ss += __shfl_xor(ss, d);
  }
  __shared__ float red[10];
  int lane = tid & 63, wave = tid >> 6;
  if (lane == 0) { red[wave] = s; red[4 + wave] = ss; }
  __syncthreads();
  if (tid == 0) {
    float S = red[0] + red[1] + red[2] + red[3];
    float SS = red[4] + red[5] + red[6] + red[7];
    float mean = S * (1.f / 65536.f);
    float var = SS * (1.f / 65536.f) - mean * mean;
    red[8] = mean;
    red[9] = rsqrtf(var + 1e-6f);
  }
  __syncthreads();
  float mean = red[8], rstd = red[9];

  float a[16], bb[16];
#pragma unroll
  for (int c = 0; c < 16; ++c) {
    float gm = gamma[grp * 16 + c];
    float bt = beta[grp * 16 + c];
    a[c] = gm * rstd;
    bb[c] = bt - mean * a[c];
  }
  u16* hb = ht + (long)b * 4096 * 256 + grp * 16;
  for (int it = 0; it < 16; ++it) {
    int n = it * 256 + tid;
    __align__(16) u16 tmp[16];
#pragma unroll
    for (int c = 0; c < 16; ++c)
      tmp[c] = f2bf(xg[(long)c * 4096 + n] * a[c] + bb[c]);
    u16* dst = hb + (long)n * 256;
    ((uint4*)dst)[0] = ((uint4*)tmp)[0];
    ((uint4*)dst)[1] = ((uint4*)tmp)[1];
  }
}

// ---------------- generic 64x64-tile bf16 GEMM: D[m][n] = sum_k A[m][k] * Bt[n][k] ----------------
// MODE 0: out bf16, += bias[n]   (Q,K: out q_t[m=pos][n=o])
// MODE 1: out bf16, += bias[m]   (V:   out v_c[m=o][n=pos])
// MODE 2: out fp32, += bias[m] + resid[addr]  (proj + residual)
template<int MODE>
__global__ __launch_bounds__(256) void gemm64(
    const u16* __restrict__ A, const u16* __restrict__ Bt,
    void* __restrict__ outp, const float* __restrict__ bias,
    const float* __restrict__ resid,
    int K, int lda, int ldb, int ldc,
    long sAZ, long sBZ, long sOZ) {
  __shared__ __align__(16) u16 as[64 * 64];
  __shared__ __align__(16) u16 bs[64 * 64];
  int tid = threadIdx.x;
  int lane = tid & 63, wave = tid >> 6;
  int g = lane >> 4, lr = lane & 15;
  int wm = wave >> 1, wn = wave & 1;
  int z = blockIdx.z;
  const u16* Ab = A + (long)z * sAZ + (long)blockIdx.x * 64 * lda;
  const u16* Bb = Bt + (long)z * sBZ + (long)blockIdx.y * 64 * ldb;

  f32x4 zero = {0.f, 0.f, 0.f, 0.f};
  f32x4 acc[2][2];
#pragma unroll
  for (int i = 0; i < 2; ++i)
#pragma unroll
    for (int j = 0; j < 2; ++j) acc[i][j] = zero;

  for (int k0 = 0; k0 < K; k0 += 64) {
    stage_swz<128, 2>(as, Ab + k0, lda, tid);
    stage_swz<128, 2>(bs, Bb + k0, ldb, tid);
    __syncthreads();
#pragma unroll
    for (int ks = 0; ks < 2; ++ks) {
      int kb = ks * 64 + g * 16;
      bf16x8 a0 = ldfrag<128>(as, wm * 32 + lr, kb);
      bf16x8 a1 = ldfrag<128>(as, wm * 32 + 16 + lr, kb);
      bf16x8 b0 = ldfrag<128>(bs, wn * 32 + lr, kb);
      bf16x8 b1 = ldfrag<128>(bs, wn * 32 + 16 + lr, kb);
      acc[0][0] = mfma16(a0, b0, acc[0][0]);
      acc[0][1] = mfma16(a0, b1, acc[0][1]);
      acc[1][0] = mfma16(a1, b0, acc[1][0]);
      acc[1][1] = mfma16(a1, b1, acc[1][1]);
    }
    __syncthreads();
  }

  int mb = blockIdx.x * 64 + wm * 32;
  int nb = blockIdx.y * 64 + wn * 32;
#pragma unroll
  for (int mi = 0; mi < 2; ++mi)
#pragma unroll
    for (int ni = 0; ni < 2; ++ni)
#pragma unroll
      for (int e = 0; e < 4; ++e) {
        int m = mb + mi * 16 + 4 * g + e;   // D row = 4*(lane>>4)+reg  [m89]
        int n = nb + ni * 16 + lr;          // D col = lane&15
        float v = acc[mi][ni][e];
        long addr = (long)z * sOZ + (long)m * ldc + n;
        if (MODE == 0)      ((u16*)outp)[addr] = f2bf(v + bias[n]);
        else if (MODE == 1) ((u16*)outp)[addr] = f2bf(v + bias[m]);
        else                ((float*)outp)[addr] = v + bias[m] + resid[addr];
      }
}

// ---------------- flash attention: S=q_t k_t^T /16, online softmax, O = P v ----------------
// block: 64 query rows (4 waves x 16), loops 64-wide j tiles over N=4096.
__global__ __launch_bounds__(256) void attn_flash(
    const u16* __restrict__ qt, const u16* __restrict__ kt,
    const u16* __restrict__ vc, u16* __restrict__ ot) {
  __shared__ __align__(16) u16 qs[64 * 256];   // [i][c] swizzled, 32KB
  __shared__ __align__(16) u16 ks[64 * 256];   // [j][c] swizzled, 32KB
  __shared__ __align__(16) u16 vs[256 * 64];   // [c][j] swizzled, 32KB
  __shared__ __align__(16) u16 ps[4][16 * 64]; // per-wave P [i][j], 2KB each

  int tid = threadIdx.x;
  int lane = tid & 63, wave = tid >> 6;
  int g = lane >> 4, lr = lane & 15;
  long b = blockIdx.y;
  int i0 = blockIdx.x * 64;

  const u16* qb = qt + (b * 4096 + i0) * 256;
  const u16* kb = kt + b * 4096 * 256;
  const u16* vb = vc + b * 256 * 4096;
  u16* ob = ot + (b * 4096 + i0) * 256;

  stage_swz<512, 8>(qs, qb, 256, tid);

  f32x4 zero = {0.f, 0.f, 0.f, 0.f};
  f32x4 o[16];
#pragma unroll
  for (int t = 0; t < 16; ++t) o[t] = zero;
  float mrun[4] = {-1e30f, -1e30f, -1e30f, -1e30f};
  float lsum[4] = {0.f, 0.f, 0.f, 0.f};
  const float L2E = 1.44269504f;

  for (int j0 = 0; j0 < 4096; j0 += 64) {
    __syncthreads();                                  // prev-iter reads done before overwrite
    stage_swz<512, 8>(ks, kb + (long)j0 * 256, 256, tid);
    stage_swz<128, 8>(vs, vb + j0, 4096, tid);
    __syncthreads();                                  // staging (vmcnt) drained

    // S tile: wave rows = wave*16..+15, cols j0..j0+63
    f32x4 s[4];
#pragma unroll
    for (int jt = 0; jt < 4; ++jt) s[jt] = zero;
#pragma unroll
    for (int kk = 0; kk < 8; ++kk) {
      int kbyt = kk * 64 + g * 16;
      bf16x8 qa = ldfrag<512>(qs, wave * 16 + lr, kbyt);
#pragma unroll
      for (int jt = 0; jt < 4; ++jt) {
        bf16x8 kf = ldfrag<512>(ks, jt * 16 + lr, kbyt);
        s[jt] = mfma16(qa, kf, s[jt]);
      }
    }

    // online softmax over rows 4g+e (reduce across 16-lane group = cols)
    float mloc[4] = {-1e30f, -1e30f, -1e30f, -1e30f};
#pragma unroll
    for (int jt = 0; jt < 4; ++jt)
#pragma unroll
      for (int e = 0; e < 4; ++e) {
        s[jt][e] *= 0.0625f;                      // C^-0.5
        mloc[e] = fmaxf(mloc[e], s[jt][e]);
      }
#pragma unroll
    for (int d = 1; d < 16; d <<= 1)
#pragma unroll
      for (int e = 0; e < 4; ++e)
        mloc[e] = fmaxf(mloc[e], __shfl_xor(mloc[e], d));

    float alpha[4];
#pragma unroll
    for (int e = 0; e < 4; ++e) {
      float mn = fmaxf(mrun[e], mloc[e]);
      alpha[e] = exp2f((mrun[e] - mn) * L2E);
      mrun[e] = mn;
    }

    u16* pw = ps[wave];
    float rsum[4] = {0.f, 0.f, 0.f, 0.f};
#pragma unroll
    for (int jt = 0; jt < 4; ++jt)
#pragma unroll
      for (int e = 0; e < 4; ++e) {
        float p = exp2f((s[jt][e] - mrun[e]) * L2E);
        rsum[e] += p;
        int row = 4 * g + e;
        int cb = ((jt * 16 + lr) * 2) ^ ((row & 7) << 4);
        *(u16*)((char*)pw + row * 128 + cb) = f2bf(p);
      }
#pragma unroll
    for (int d = 1; d < 16; d <<= 1)
#pragma unroll
      for (int e = 0; e < 4; ++e)
        rsum[e] += __shfl_xor(rsum[e], d);
#pragma unroll
    for (int e = 0; e < 4; ++e)
      lsum[e] = lsum[e] * alpha[e] + rsum[e];
#pragma unroll
    for (int t = 0; t < 16; ++t)
#pragma unroll
      for (int e = 0; e < 4; ++e)
        o[t][e] *= alpha[e];

    // PV: O[i][c] += P[i][j] * v[c][j]   (P re-read as A-frag from wave-private LDS)
#pragma unroll
    for (int ks2 = 0; ks2 < 2; ++ks2) {
      bf16x8 pa = ldfrag<128>(pw, lr, ks2 * 64 + g * 16);
#pragma unroll
      for (int ct = 0; ct < 16; ++ct) {
        bf16x8 vf = ldfrag<128>(vs, ct * 16 + lr, ks2 * 64 + g * 16);
        o[ct] = mfma16(pa, vf, o[ct]);
      }
    }
  }

#pragma unroll
  for (int ct = 0; ct < 16; ++ct)
#pragma unroll
    for (int e = 0; e < 4; ++e) {
      float val = o[ct][e] / lsum[e];
      int il = wave * 16 + 4 * g + e;
      int c = ct * 16 + lr;
      ob[(long)il * 256 + c] = f2bf(val);
    }
}

// ---------------- launcher ----------------
extern "C" void kernel_launch(void* const* d_in, const int* in_sizes, int n_in,
                              void* d_out, int out_size, void* d_ws, size_t ws_size,
                              hipStream_t stream) {
  const float* x     = (const float*)d_in[0];
  const float* gamma = (const float*)d_in[1];
  const float* beta  = (const float*)d_in[2];
  const float* wq = (const float*)d_in[3];
  const float* bq = (const float*)d_in[4];
  const float* wk = (const float*)d_in[5];
  const float* bk = (const float*)d_in[6];
  const float* wv = (const float*)d_in[7];
  const float* bv = (const float*)d_in[8];
  const float* wp = (const float*)d_in[9];
  const float* bp = (const float*)d_in[10];

  char* ws = (char*)d_ws;
  const long SZ = 16777216;            // one [B][N][C] bf16 tensor
  u16* ht  = (u16*)(ws);
  u16* qtb = (u16*)(ws + SZ);
  u16* ktb = (u16*)(ws + 2 * SZ);
  u16* vcb = (u16*)(ws + 3 * SZ);
  u16* wbf = (u16*)(ws + 4 * SZ);      // wq|wk|wv|wp, 65536 u16 each
  u16* otb = ht;                       // h dead after QKV; reuse for attn output

  convert_w<<<1024, 256, 0, stream>>>(wq, wk, wv, wp, wbf);
  gn_kernel<<<128, 256, 0, stream>>>(x, gamma, beta, ht);

  dim3 gq(512, 4, 1);   // M=B*N=32768 rows, Nn=256
  gemm64<0><<<gq, 256, 0, stream>>>(ht, wbf,         qtb, bq, nullptr, 256, 256, 256, 256, 0, 0, 0);
  gemm64<0><<<gq, 256, 0, stream>>>(ht, wbf + 65536, ktb, bk, nullptr, 256, 256, 256, 256, 0, 0, 0);

  dim3 gv(4, 64, 8);    // M=256 (o), Nn=4096 (pos), per batch
  gemm64<1><<<gv, 256, 0, stream>>>(wbf + 2 * 65536, ht, vcb, bv, nullptr,
                                    256, 256, 256, 4096, 0, (long)4096 * 256, (long)256 * 4096);

  dim3 gf(64, 8, 1);
  attn_flash<<<gf, 256, 0, stream>>>(qtb, ktb, vcb, otb);

  dim3 gp(4, 64, 8);
  gemm64<2><<<gp, 256, 0, stream>>>(wbf + 3 * 65536, otb, d_out, bp, x,
                                    256, 256, 256, 4096, 0, (long)4096 * 256, (long)256 * 4096);
}

// Round 2
// 396.319 us; speedup vs baseline: 1.4168x; 1.4168x over previous
//
#include <hip/hip_runtime.h>
#include <hip/hip_bf16.h>

// AttnBlock2d: GN -> q/k/v 1x1conv -> softmax(q^T k / sqrt(C)) -> v@alpha -> proj -> +x
// B=8, C=256, N=H*W=4096. bf16 MFMA pipeline, fp32 accumulation.
// R2: Q-in-regs flash attn, 8 waves/block, K/V double-buffer (1 barrier/iter),
//     defer-max, scale folded into Q gemm, fused QKV gemm, XCD-aligned batches.

typedef unsigned int u32;
typedef unsigned short u16;
typedef __bf16 bf16x8 __attribute__((ext_vector_type(8)));
typedef float f32x4 __attribute__((ext_vector_type(4)));

#define GAS __attribute__((address_space(1)))
#define LAS __attribute__((address_space(3)))

__device__ __forceinline__ u16 f2bf(float f) {
  union { float f; u32 u; } v; v.f = f;
  return (u16)((v.u + 0x7fffu + ((v.u >> 16) & 1u)) >> 16);
}

__device__ __forceinline__ f32x4 mfma16(bf16x8 a, bf16x8 b, f32x4 c) {
  return __builtin_amdgcn_mfma_f32_16x16x32_bf16(a, b, c, 0, 0, 0);
}

// Stage a [ROWS][ROWB bytes] row-major bf16 tile into linear LDS via global_load_lds,
// XOR swizzle applied on the SOURCE side (linear dest + inverse-swz source).
// Semantic colbyte of linear slot s in row r is s ^ ((r&7)<<4).
template<int ROWB, int ITERS, int NT>
__device__ __forceinline__ void stage_swz(u16* lds, const u16* g, int ldg, int tid) {
#pragma unroll
  for (int it = 0; it < ITERS; ++it) {
    int idx = it * NT + tid;
    int off = idx * 16;                 // linear LDS byte offset
    int row = off / ROWB;
    int slot = off % ROWB;
    int sem = slot ^ ((row & 7) << 4);  // semantic byte-in-row
    const u16* src = g + (long)row * ldg + (sem >> 1);
    u16* dst = lds + (long)(idx & ~63) * 8;   // wave-uniform base; HW adds lane*16B
    __builtin_amdgcn_global_load_lds((const GAS u32*)src, (LAS u32*)dst, 16, 0, 0);
  }
}

// Read a 16B MFMA fragment from a swizzled tile: semantic (row, kbyte) -> swizzled addr.
template<int ROWB>
__device__ __forceinline__ bf16x8 ldfrag(const u16* lds, int row, int kbyte) {
  int off = row * ROWB + (kbyte ^ ((row & 7) << 4));
  return *(const bf16x8*)((const char*)lds + off);
}

// ---------------- weight fp32 -> bf16 ----------------
__global__ __launch_bounds__(256) void convert_w(
    const float* __restrict__ w0, const float* __restrict__ w1,
    const float* __restrict__ w2, const float* __restrict__ w3,
    u16* __restrict__ out) {
  int i = blockIdx.x * 256 + threadIdx.x;      // 0 .. 262143
  int seg = i >> 16, idx = i & 65535;
  const float* w = seg == 0 ? w0 : seg == 1 ? w1 : seg == 2 ? w2 : w3;
  out[i] = f2bf(w[idx]);
}

// ---------------- GroupNorm: x [B][C][N] fp32 -> h_t [B][N][C] bf16 ----------------
__global__ __launch_bounds__(256) void gn_kernel(
    const float* __restrict__ x, const float* __restrict__ gamma,
    const float* __restrict__ beta, u16* __restrict__ ht) {
  int tid = threadIdx.x;
  int b = blockIdx.x >> 4;
  int grp = blockIdx.x & 15;
  const float* xg = x + ((long)b * 256 + grp * 16) * 4096;

  float s = 0.f, ss = 0.f;
  const float4* x4 = (const float4*)xg;
#pragma unroll 4
  for (int it = 0; it < 64; ++it) {
    float4 v = x4[it * 256 + tid];
    s += v.x + v.y + v.z + v.w;
    ss += v.x * v.x + v.y * v.y + v.z * v.z + v.w * v.w;
  }
#pragma unroll
  for (int d = 1; d < 64; d <<= 1) {
    s += __shfl_xor(s, d);
    ss += __shfl_xor(ss, d);
  }
  __shared__ float red[10];
  int lane = tid & 63, wave = tid >> 6;
  if (lane == 0) { red[wave] = s; red[4 + wave] = ss; }
  __syncthreads();
  if (tid == 0) {
    float S = red[0] + red[1] + red[2] + red[3];
    float SS = red[4] + red[5] + red[6] + red[7];
    float mean = S * (1.f / 65536.f);
    float var = SS * (1.f / 65536.f) - mean * mean;
    red[8] = mean;
    red[9] = rsqrtf(var + 1e-6f);
  }
  __syncthreads();
  float mean = red[8], rstd = red[9];

  float a[16], bb[16];
#pragma unroll
  for (int c = 0; c < 16; ++c) {
    float gm = gamma[grp * 16 + c];
    float bt = beta[grp * 16 + c];
    a[c] = gm * rstd;
    bb[c] = bt - mean * a[c];
  }
  u16* hb = ht + (long)b * 4096 * 256 + grp * 16;
  for (int it = 0; it < 16; ++it) {
    int n = it * 256 + tid;
    __align__(16) u16 tmp[16];
#pragma unroll
    for (int c = 0; c < 16; ++c)
      tmp[c] = f2bf(xg[(long)c * 4096 + n] * a[c] + bb[c]);
    u16* dst = hb + (long)n * 256;
    ((uint4*)dst)[0] = ((uint4*)tmp)[0];
    ((uint4*)dst)[1] = ((uint4*)tmp)[1];
  }
}

// ---------------- fused QKV GEMM ----------------
// D[m=pos][n=o] = sum_c ht[m][c] * w[n][c]  for w in {wq,wk,wv}
// q_t, k_t out [pos][o] bf16 (q scaled by C^-0.5*log2e); v_c out [b][o][pos] bf16.
__global__ __launch_bounds__(256) void gemm_qkv(
    const u16* __restrict__ ht, const u16* __restrict__ wbf,
    u16* __restrict__ qtb, u16* __restrict__ ktb, u16* __restrict__ vcb,
    const float* __restrict__ bq, const float* __restrict__ bk,
    const float* __restrict__ bv) {
  __shared__ __align__(16) u16 as[64 * 64];
  __shared__ __align__(16) u16 bqs[64 * 64];
  __shared__ __align__(16) u16 bks[64 * 64];
  __shared__ __align__(16) u16 bvs[64 * 64];
  int tid = threadIdx.x;
  int lane = tid & 63, wave = tid >> 6;
  int g = lane >> 4, lr = lane & 15;
  int wm = wave >> 1, wn = wave & 1;
  const u16* Ab = ht + (long)blockIdx.x * 64 * 256;
  const u16* Wq = wbf + (long)blockIdx.y * 64 * 256;

  f32x4 zero = {0.f, 0.f, 0.f, 0.f};
  f32x4 acc[3][2][2];
#pragma unroll
  for (int w = 0; w < 3; ++w)
#pragma unroll
    for (int i = 0; i < 2; ++i)
#pragma unroll
      for (int j = 0; j < 2; ++j) acc[w][i][j] = zero;

  for (int k0 = 0; k0 < 256; k0 += 64) {
    stage_swz<128, 2, 256>(as, Ab + k0, 256, tid);
    stage_swz<128, 2, 256>(bqs, Wq + k0, 256, tid);
    stage_swz<128, 2, 256>(bks, Wq + 65536 + k0, 256, tid);
    stage_swz<128, 2, 256>(bvs, Wq + 131072 + k0, 256, tid);
    __syncthreads();
#pragma unroll
    for (int ks = 0; ks < 2; ++ks) {
      int kb = ks * 64 + g * 16;
      bf16x8 a0 = ldfrag<128>(as, wm * 32 + lr, kb);
      bf16x8 a1 = ldfrag<128>(as, wm * 32 + 16 + lr, kb);
      __builtin_amdgcn_s_setprio(1);
      {
        bf16x8 b0 = ldfrag<128>(bqs, wn * 32 + lr, kb);
        bf16x8 b1 = ldfrag<128>(bqs, wn * 32 + 16 + lr, kb);
        acc[0][0][0] = mfma16(a0, b0, acc[0][0][0]);
        acc[0][0][1] = mfma16(a0, b1, acc[0][0][1]);
        acc[0][1][0] = mfma16(a1, b0, acc[0][1][0]);
        acc[0][1][1] = mfma16(a1, b1, acc[0][1][1]);
      }
      {
        bf16x8 b0 = ldfrag<128>(bks, wn * 32 + lr, kb);
        bf16x8 b1 = ldfrag<128>(bks, wn * 32 + 16 + lr, kb);
        acc[1][0][0] = mfma16(a0, b0, acc[1][0][0]);
        acc[1][0][1] = mfma16(a0, b1, acc[1][0][1]);
        acc[1][1][0] = mfma16(a1, b0, acc[1][1][0]);
        acc[1][1][1] = mfma16(a1, b1, acc[1][1][1]);
      }
      {
        bf16x8 b0 = ldfrag<128>(bvs, wn * 32 + lr, kb);
        bf16x8 b1 = ldfrag<128>(bvs, wn * 32 + 16 + lr, kb);
        acc[2][0][0] = mfma16(a0, b0, acc[2][0][0]);
        acc[2][0][1] = mfma16(a0, b1, acc[2][0][1]);
        acc[2][1][0] = mfma16(a1, b0, acc[2][1][0]);
        acc[2][1][1] = mfma16(a1, b1, acc[2][1][1]);
      }
      __builtin_amdgcn_s_setprio(0);
    }
    __syncthreads();
  }

  const float QSC = 0.0625f * 1.44269504f;
  int mb = blockIdx.x * 64 + wm * 32;
  int nb = blockIdx.y * 64 + wn * 32;
  int b_ = mb >> 12;
  int posb = mb & 4095;
#pragma unroll
  for (int mi = 0; mi < 2; ++mi)
#pragma unroll
    for (int ni = 0; ni < 2; ++ni) {
      int n = nb + ni * 16 + lr;
      __align__(8) u16 v4[4];
#pragma unroll
      for (int e = 0; e < 4; ++e) {
        int m = mb + mi * 16 + 4 * g + e;   // D row = 4*(lane>>4)+reg
        long addr = (long)m * 256 + n;
        qtb[addr] = f2bf((acc[0][mi][ni][e] + bq[n]) * QSC);
        ktb[addr] = f2bf(acc[1][mi][ni][e] + bk[n]);
        v4[e] = f2bf(acc[2][mi][ni][e] + bv[n]);
      }
      int pos0 = posb + mi * 16 + 4 * g;
      *(uint2*)(vcb + (long)b_ * 1048576 + (long)n * 4096 + pos0) = *(uint2*)v4;
    }
}

// ---------------- proj GEMM + residual: D[m=o][n=pos] fp32 ----------------
__global__ __launch_bounds__(256) void gemm_proj(
    const u16* __restrict__ A, const u16* __restrict__ Bt,
    float* __restrict__ outp, const float* __restrict__ bias,
    const float* __restrict__ resid) {
  __shared__ __align__(16) u16 as[64 * 64];
  __shared__ __align__(16) u16 bs[64 * 64];
  int tid = threadIdx.x;
  int lane = tid & 63, wave = tid >> 6;
  int g = lane >> 4, lr = lane & 15;
  int wm = wave >> 1, wn = wave & 1;
  int z = blockIdx.z;
  const u16* Ab = A + (long)blockIdx.x * 64 * 256;
  const u16* Bb = Bt + (long)z * 4096 * 256 + (long)blockIdx.y * 64 * 256;

  f32x4 zero = {0.f, 0.f, 0.f, 0.f};
  f32x4 acc[2][2];
#pragma unroll
  for (int i = 0; i < 2; ++i)
#pragma unroll
    for (int j = 0; j < 2; ++j) acc[i][j] = zero;

  for (int k0 = 0; k0 < 256; k0 += 64) {
    stage_swz<128, 2, 256>(as, Ab + k0, 256, tid);
    stage_swz<128, 2, 256>(bs, Bb + k0, 256, tid);
    __syncthreads();
#pragma unroll
    for (int ks = 0; ks < 2; ++ks) {
      int kb = ks * 64 + g * 16;
      bf16x8 a0 = ldfrag<128>(as, wm * 32 + lr, kb);
      bf16x8 a1 = ldfrag<128>(as, wm * 32 + 16 + lr, kb);
      bf16x8 b0 = ldfrag<128>(bs, wn * 32 + lr, kb);
      bf16x8 b1 = ldfrag<128>(bs, wn * 32 + 16 + lr, kb);
      acc[0][0] = mfma16(a0, b0, acc[0][0]);
      acc[0][1] = mfma16(a0, b1, acc[0][1]);
      acc[1][0] = mfma16(a1, b0, acc[1][0]);
      acc[1][1] = mfma16(a1, b1, acc[1][1]);
    }
    __syncthreads();
  }

  int mb = blockIdx.x * 64 + wm * 32;
  int nb = blockIdx.y * 64 + wn * 32;
#pragma unroll
  for (int mi = 0; mi < 2; ++mi)
#pragma unroll
    for (int ni = 0; ni < 2; ++ni)
#pragma unroll
      for (int e = 0; e < 4; ++e) {
        int m = mb + mi * 16 + 4 * g + e;
        int n = nb + ni * 16 + lr;
        long addr = (long)z * 1048576 + (long)m * 4096 + n;
        outp[addr] = acc[mi][ni][e] + bias[m] + resid[addr];
      }
}

// ---------------- flash attention ----------------
// 256 blocks (b = bid&7 -> XCD-aligned), 8 waves, 128 q-rows/block (16/wave).
// Q in registers; K/V double-buffered LDS; 1 barrier/iter; defer-max softmax.
// q_t comes prescaled by C^-0.5*log2e, so S is in log2 units.
__global__ __launch_bounds__(512) void attn_flash(
    const u16* __restrict__ qt, const u16* __restrict__ kt,
    const u16* __restrict__ vc, u16* __restrict__ ot) {
  __shared__ __align__(16) u16 ks[2][64 * 256];   // [j][c] swizzled, 2x32KB
  __shared__ __align__(16) u16 vs[2][256 * 64];   // [c][j] swizzled, 2x32KB
  __shared__ __align__(16) u16 ps[8][16 * 64];    // per-wave P [i][j], 2KB each

  int tid = threadIdx.x;
  int lane = tid & 63, wave = tid >> 6;
  int g = lane >> 4, lr = lane & 15;
  int bid = blockIdx.x;
  long b = bid & 7;                // XCD-aligned: batch b's blocks all land on XCD b
  int i0 = (bid >> 3) * 128;

  const u16* kb = kt + b * 4096 * 256;
  const u16* vb = vc + b * 256 * 4096;

  // Q rows (wave*16 + lr) into registers: frag kk covers k = kk*32 + 8g + e
  const u16* qrow = qt + ((b * 4096 + i0 + wave * 16 + lr) << 8) + g * 8;
  bf16x8 qreg[8];
#pragma unroll
  for (int kk = 0; kk < 8; ++kk)
    qreg[kk] = *(const bf16x8*)(qrow + kk * 32);

  f32x4 zero = {0.f, 0.f, 0.f, 0.f};
  f32x4 o[16];
#pragma unroll
  for (int t = 0; t < 16; ++t) o[t] = zero;
  float mrun[4] = {-3e38f, -3e38f, -3e38f, -3e38f};
  float lsum[4] = {0.f, 0.f, 0.f, 0.f};

  stage_swz<512, 4, 512>(ks[0], kb, 256, tid);
  stage_swz<128, 4, 512>(vs[0], vb, 4096, tid);
  __syncthreads();

  for (int t = 0; t < 64; ++t) {
    int cur = t & 1, nxt = cur ^ 1;
    int jn = ((t + 1) & 63) * 64;
    // issue next tile's loads; they fly under this iter's compute
    stage_swz<512, 4, 512>(ks[nxt], kb + (long)jn * 256, 256, tid);
    stage_swz<128, 4, 512>(vs[nxt], vb + jn, 4096, tid);

    // S = q k^T (log2 units): rows 4g+e of wave's 16, cols jt*16+lr
    f32x4 s[4];
#pragma unroll
    for (int jt = 0; jt < 4; ++jt) s[jt] = zero;
    __builtin_amdgcn_s_setprio(1);
#pragma unroll
    for (int kk = 0; kk < 8; ++kk) {
      int kbyt = kk * 64 + g * 16;
#pragma unroll
      for (int jt = 0; jt < 4; ++jt) {
        bf16x8 kf = ldfrag<512>(ks[cur], jt * 16 + lr, kbyt);
        s[jt] = mfma16(qreg[kk], kf, s[jt]);
      }
    }
    __builtin_amdgcn_s_setprio(0);

    // row max across the 16-lane group
    float mloc[4];
#pragma unroll
    for (int e = 0; e < 4; ++e)
      mloc[e] = fmaxf(fmaxf(s[0][e], s[1][e]), fmaxf(s[2][e], s[3][e]));
#pragma unroll
    for (int d = 1; d < 16; d <<= 1)
#pragma unroll
      for (int e = 0; e < 4; ++e)
        mloc[e] = fmaxf(mloc[e], __shfl_xor(mloc[e], d));

    // defer-max: only rescale when a row's max grew by more than 8 (log2)
    int small = (mloc[0] - mrun[0] <= 8.f) & (mloc[1] - mrun[1] <= 8.f) &
                (mloc[2] - mrun[2] <= 8.f) & (mloc[3] - mrun[3] <= 8.f);
    if (!__all(small)) {
      float al[4];
#pragma unroll
      for (int e = 0; e < 4; ++e) {
        float mn = fmaxf(mrun[e], mloc[e]);
        al[e] = exp2f(mrun[e] - mn);
        mrun[e] = mn;
        lsum[e] *= al[e];
      }
#pragma unroll
      for (int ct = 0; ct < 16; ++ct)
#pragma unroll
        for (int e = 0; e < 4; ++e) o[ct][e] *= al[e];
    }

    // P = exp2(S - m), per-lane partial lsum (reduced once at the end)
    u16* pw = ps[wave];
#pragma unroll
    for (int jt = 0; jt < 4; ++jt)
#pragma unroll
      for (int e = 0; e < 4; ++e) {
        float p = exp2f(s[jt][e] - mrun[e]);
        lsum[e] += p;
        int row = 4 * g + e;
        int cb = ((jt * 16 + lr) * 2) ^ ((row & 7) << 4);
        *(u16*)((char*)pw + row * 128 + cb) = f2bf(p);
      }

    // PV: O[i][c] += P[i][j] * v[c][j]
    __builtin_amdgcn_s_setprio(1);
#pragma unroll
    for (int ks2 = 0; ks2 < 2; ++ks2) {
      bf16x8 pa = ldfrag<128>(pw, lr, ks2 * 64 + g * 16);
#pragma unroll
      for (int ct = 0; ct < 16; ++ct) {
        bf16x8 vf = ldfrag<128>(vs[cur], ct * 16 + lr, ks2 * 64 + g * 16);
        o[ct] = mfma16(pa, vf, o[ct]);
      }
    }
    __builtin_amdgcn_s_setprio(0);

    __syncthreads();   // next buffer staged (vmcnt drained) + all reads of cur done
  }

  // final: reduce per-lane lsum across the 16-group, normalize, store
#pragma unroll
  for (int d = 1; d < 16; d <<= 1)
#pragma unroll
    for (int e = 0; e < 4; ++e)
      lsum[e] += __shfl_xor(lsum[e], d);
  float rl[4];
#pragma unroll
  for (int e = 0; e < 4; ++e) rl[e] = 1.0f / lsum[e];

  u16* ob = ot + ((b * 4096 + i0 + wave * 16) << 8);
#pragma unroll
  for (int ct = 0; ct < 16; ++ct)
#pragma unroll
    for (int e = 0; e < 4; ++e) {
      int il = 4 * g + e;
      int c = ct * 16 + lr;
      ob[(long)il * 256 + c] = f2bf(o[ct][e] * rl[e]);
    }
}

// ---------------- launcher ----------------
extern "C" void kernel_launch(void* const* d_in, const int* in_sizes, int n_in,
                              void* d_out, int out_size, void* d_ws, size_t ws_size,
                              hipStream_t stream) {
  const float* x     = (const float*)d_in[0];
  const float* gamma = (const float*)d_in[1];
  const float* beta  = (const float*)d_in[2];
  const float* wq = (const float*)d_in[3];
  const float* bq = (const float*)d_in[4];
  const float* wk = (const float*)d_in[5];
  const float* bk = (const float*)d_in[6];
  const float* wv = (const float*)d_in[7];
  const float* bv = (const float*)d_in[8];
  const float* wp = (const float*)d_in[9];
  const float* bp = (const float*)d_in[10];

  char* ws = (char*)d_ws;
  const long SZ = 16777216;            // one [B][N][C] bf16 tensor
  u16* ht  = (u16*)(ws);
  u16* qtb = (u16*)(ws + SZ);
  u16* ktb = (u16*)(ws + 2 * SZ);
  u16* vcb = (u16*)(ws + 3 * SZ);
  u16* wbf = (u16*)(ws + 4 * SZ);      // wq|wk|wv|wp, 65536 u16 each
  u16* otb = ht;                       // h dead after QKV; reuse for attn output

  convert_w<<<1024, 256, 0, stream>>>(wq, wk, wv, wp, wbf);
  gn_kernel<<<128, 256, 0, stream>>>(x, gamma, beta, ht);

  dim3 gq(512, 4, 1);   // M=B*N=32768 rows, Nn=256
  gemm_qkv<<<gq, 256, 0, stream>>>(ht, wbf, qtb, ktb, vcb, bq, bk, bv);

  attn_flash<<<256, 512, 0, stream>>>(qtb, ktb, vcb, otb);

  dim3 gp(4, 64, 8);
  gemm_proj<<<gp, 256, 0, stream>>>(wbf + 3 * 65536, otb, (float*)d_out, bp, x);
}